// Round 3
// baseline (96.390 us; speedup 1.0000x reference)
//
#include <hip/hip_runtime.h>
#include <math.h>

// KAN_layer: B=8192, IN_F=OUT_F=1024, GRID=5. idx_in == identity => x = X.
// spline is piecewise-linear with integer breakpoints in t = 2*clamp(x,-1,1)+2:
//   s(t) = c0 + sum_i (c[i+1]-c[i]) * clamp(t - i, 0, 1)   (exact for G=5)
//
// v3b: v3 with the compile fix — __builtin_nontemporal_* requires a clang
// vector type, not HIP's float4 struct. Use ext_vector_type(4).
// Theory (R2): dur_us ~= 75us harness floor (256MiB ws poison ~43us + out
// poison ~5.4us + tiny restore dispatches) + ~14us kernel; kernel floor ~11us
// (67MB mixed R/W @ ~6TB/s). v3 targets the last ~3us:
//   - nontemporal load X / store Y (pure streams, zero reuse)
//   - no LDS staging / no __syncthreads; params via coalesced 16B loads
//   - 2048 blocks x 4 rows

#define B_ROWS   8192
#define N_FEAT   1024
#define N_BLOCKS 2048
#define ROWS_PER_BLOCK (B_ROWS / N_BLOCKS)   // 4

typedef float floatx4 __attribute__((ext_vector_type(4)));

__global__ __launch_bounds__(256, 4) void kan_kernel(
    const float* __restrict__ X,
    const float* __restrict__ coeffs,   // (1024, 5) row-major
    const float* __restrict__ W,        // (1024, 2) row-major
    const float* __restrict__ bias,     // (1024,)
    float* __restrict__ Y)
{
    const int t    = threadIdx.x;   // 0..255
    const int col0 = t * 4;         // this thread owns columns col0..col0+3

    const int row0 = blockIdx.x * ROWS_PER_BLOCK;

    // ---- issue the 4 X row-loads first (critical path), nontemporal ----
    floatx4 xs[ROWS_PER_BLOCK];
#pragma unroll
    for (int i = 0; i < ROWS_PER_BLOCK; ++i) {
        const size_t base = (size_t)(row0 + i) * N_FEAT + col0;
        xs[i] = __builtin_nontemporal_load(
            reinterpret_cast<const floatx4*>(X + base));
    }

    // ---- per-column params via coalesced 16B loads (L2-resident) ----
    // coeffs: this thread needs floats [t*20, t*20+20) = floatx4 [t*5, t*5+5)
    const floatx4* c4 = reinterpret_cast<const floatx4*>(coeffs);
    const floatx4 cA = c4[t * 5 + 0];
    const floatx4 cB = c4[t * 5 + 1];
    const floatx4 cC = c4[t * 5 + 2];
    const floatx4 cD = c4[t * 5 + 3];
    const floatx4 cE = c4[t * 5 + 4];
    const float cf[20] = {cA.x, cA.y, cA.z, cA.w,  cB.x, cB.y, cB.z, cB.w,
                          cC.x, cC.y, cC.z, cC.w,  cD.x, cD.y, cD.z, cD.w,
                          cE.x, cE.y, cE.z, cE.w};

    // W: floats [t*8, t*8+8) = floatx4 [t*2, t*2+2)
    const floatx4* w4 = reinterpret_cast<const floatx4*>(W);
    const floatx4 wA = w4[t * 2 + 0];
    const floatx4 wB = w4[t * 2 + 1];
    const float wf[8] = {wA.x, wA.y, wA.z, wA.w,  wB.x, wB.y, wB.z, wB.w};

    // bias: floatx4 [t]
    const floatx4 bv = reinterpret_cast<const floatx4*>(bias)[t];
    const float bf[4] = {bv.x, bv.y, bv.z, bv.w};

    float c0[4], d0[4], d1[4], d2[4], d3[4], w0[4], w1[4], bb[4];
#pragma unroll
    for (int j = 0; j < 4; ++j) {
        const float a0 = cf[j * 5 + 0];
        const float a1 = cf[j * 5 + 1];
        const float a2 = cf[j * 5 + 2];
        const float a3 = cf[j * 5 + 3];
        const float a4 = cf[j * 5 + 4];
        c0[j] = a0;
        d0[j] = a1 - a0;
        d1[j] = a2 - a1;
        d2[j] = a3 - a2;
        d3[j] = a4 - a3;
        w0[j] = wf[j * 2 + 0];
        w1[j] = wf[j * 2 + 1];
        bb[j] = bf[j];
    }

    // ---- compute + nontemporal store per row ----
#pragma unroll
    for (int i = 0; i < ROWS_PER_BLOCK; ++i) {
        const size_t base = (size_t)(row0 + i) * N_FEAT + col0;
        const float xv[4] = {xs[i].x, xs[i].y, xs[i].z, xs[i].w};
        float ys[4];

#pragma unroll
        for (int j = 0; j < 4; ++j) {
            const float x = xv[j];

            // silu(x) = x * sigmoid(x)
            const float sig  = 1.0f / (1.0f + __expf(-x));
            const float silu = x * sig;

            // b-spline linear via ramp sum (exact for G=5)
            const float xc = fminf(fmaxf(x, -1.0f), 1.0f);
            const float tt = fmaf(2.0f, xc, 2.0f);            // [0,4]
            const float r0 = fminf(tt, 1.0f);                  // tt >= 0 already
            const float r1 = fminf(fmaxf(tt - 1.0f, 0.0f), 1.0f);
            const float r2 = fminf(fmaxf(tt - 2.0f, 0.0f), 1.0f);
            const float r3 = fminf(fmaxf(tt - 3.0f, 0.0f), 1.0f);
            float s = c0[j];
            s = fmaf(d0[j], r0, s);
            s = fmaf(d1[j], r1, s);
            s = fmaf(d2[j], r2, s);
            s = fmaf(d3[j], r3, s);

            ys[j] = fmaf(silu, w0[j], fmaf(s, w1[j], bb[j]));
        }

        floatx4 yv;
        yv.x = ys[0]; yv.y = ys[1]; yv.z = ys[2]; yv.w = ys[3];
        __builtin_nontemporal_store(yv, reinterpret_cast<floatx4*>(Y + base));
    }
}

extern "C" void kernel_launch(void* const* d_in, const int* in_sizes, int n_in,
                              void* d_out, int out_size, void* d_ws, size_t ws_size,
                              hipStream_t stream) {
    const float* X      = (const float*)d_in[0];   // (8192, 1024)
    const float* coeffs = (const float*)d_in[1];   // (1024, 5)
    const float* W      = (const float*)d_in[2];   // (1024, 2)
    const float* b      = (const float*)d_in[3];   // (1024,)
    float* Y            = (float*)d_out;           // (8192, 1024)

    kan_kernel<<<N_BLOCKS, 256, 0, stream>>>(X, coeffs, W, b, Y);
}

// Round 4
// 90.838 us; speedup vs baseline: 1.0611x; 1.0611x over previous
//
#include <hip/hip_runtime.h>
#include <math.h>

// KAN_layer: B=8192, IN_F=OUT_F=1024, GRID=5. idx_in == identity => x = X.
// spline is piecewise-linear with integer breakpoints in t = 2*clamp(x,-1,1)+2:
//   s(t) = c0 + sum_i (c[i+1]-c[i]) * clamp(t - i, 0, 1)   (exact for G=5)
//
// v4 = revert of v3b's nontemporal experiment, back to v2 (best measured,
// 90.1us). Post-mortem: nt loads/stores cost +6.3us — the nt flag bypasses
// L2 buffering of the Y write stream, dropping effective BW. Session ledger:
//   v1 (scalar-gather params, 2048 blk)        91.3 us
//   v2 (LDS-staged params, 1024 blk x 8 rows)  90.1 us  <-- this kernel
//   v3b (v2 minus LDS, plus nontemporal)       96.4 us
// v1 vs v2 delta (~1us) is noise => total is dominated by the harness floor
// (256MiB poison ~43us + out poison ~5us + tiny restore dispatches ~25-30us);
// kernel itself ~14us vs ~11us BW floor (67MB mixed R/W @ ~6TB/s).

#define B_ROWS   8192
#define N_FEAT   1024
#define N_BLOCKS 1024
#define ROWS_PER_BLOCK (B_ROWS / N_BLOCKS)   // 8

__global__ __launch_bounds__(256, 4) void kan_kernel(
    const float* __restrict__ X,
    const float* __restrict__ coeffs,   // (1024, 5) row-major
    const float* __restrict__ W,        // (1024, 2) row-major
    const float* __restrict__ bias,     // (1024,)
    float* __restrict__ Y)
{
    __shared__ float s_c[N_FEAT * 5];   // 20 KB
    __shared__ float s_w[N_FEAT * 2];   //  8 KB
    __shared__ float s_b[N_FEAT];       //  4 KB

    const int t = threadIdx.x;          // 0..255

    // ---- coalesced global->LDS staging of all per-column params ----
    {
        float4*       dc = reinterpret_cast<float4*>(s_c);
        const float4* gc = reinterpret_cast<const float4*>(coeffs);
#pragma unroll
        for (int u = 0; u < 5; ++u)     // 5120 floats = 1280 float4
            dc[u * 256 + t] = gc[u * 256 + t];

        float4*       dw = reinterpret_cast<float4*>(s_w);
        const float4* gw = reinterpret_cast<const float4*>(W);
#pragma unroll
        for (int u = 0; u < 2; ++u)     // 2048 floats = 512 float4
            dw[u * 256 + t] = gw[u * 256 + t];

        float4*       db = reinterpret_cast<float4*>(s_b);
        const float4* gb = reinterpret_cast<const float4*>(bias);
        db[t] = gb[t];                  // 1024 floats = 256 float4
    }
    __syncthreads();

    // ---- per-column params -> registers (one-time LDS reads) ----
    const int col0 = t * 4;             // this thread owns cols col0..col0+3
    float c0[4], d0[4], d1[4], d2[4], d3[4], w0[4], w1[4], bb[4];
#pragma unroll
    for (int j = 0; j < 4; ++j) {
        const int col = col0 + j;
        const float a0 = s_c[col * 5 + 0];
        const float a1 = s_c[col * 5 + 1];
        const float a2 = s_c[col * 5 + 2];
        const float a3 = s_c[col * 5 + 3];
        const float a4 = s_c[col * 5 + 4];
        c0[j] = a0;
        d0[j] = a1 - a0;
        d1[j] = a2 - a1;
        d2[j] = a3 - a2;
        d3[j] = a4 - a3;
        w0[j] = s_w[col * 2 + 0];
        w1[j] = s_w[col * 2 + 1];
        bb[j] = s_b[col];
    }

    // ---- 8 consecutive rows per block; loads batched up front ----
    const int row0 = blockIdx.x * ROWS_PER_BLOCK;

    float4 xs[ROWS_PER_BLOCK];
#pragma unroll
    for (int i = 0; i < ROWS_PER_BLOCK; ++i) {
        const size_t base = (size_t)(row0 + i) * N_FEAT + col0;
        xs[i] = *reinterpret_cast<const float4*>(X + base);
    }

#pragma unroll
    for (int i = 0; i < ROWS_PER_BLOCK; ++i) {
        const size_t base = (size_t)(row0 + i) * N_FEAT + col0;
        const float xv[4] = {xs[i].x, xs[i].y, xs[i].z, xs[i].w};
        float ys[4];

#pragma unroll
        for (int j = 0; j < 4; ++j) {
            const float x = xv[j];

            // silu(x) = x * sigmoid(x)
            const float sig  = 1.0f / (1.0f + __expf(-x));
            const float silu = x * sig;

            // b-spline linear via ramp sum (exact for G=5)
            const float xc = fminf(fmaxf(x, -1.0f), 1.0f);
            const float tt = fmaf(2.0f, xc, 2.0f);            // [0,4]
            const float r0 = fminf(tt, 1.0f);                  // tt >= 0 already
            const float r1 = fminf(fmaxf(tt - 1.0f, 0.0f), 1.0f);
            const float r2 = fminf(fmaxf(tt - 2.0f, 0.0f), 1.0f);
            const float r3 = fminf(fmaxf(tt - 3.0f, 0.0f), 1.0f);
            float s = c0[j];
            s = fmaf(d0[j], r0, s);
            s = fmaf(d1[j], r1, s);
            s = fmaf(d2[j], r2, s);
            s = fmaf(d3[j], r3, s);

            ys[j] = fmaf(silu, w0[j], fmaf(s, w1[j], bb[j]));
        }

        *reinterpret_cast<float4*>(Y + base) =
            make_float4(ys[0], ys[1], ys[2], ys[3]);
    }
}

extern "C" void kernel_launch(void* const* d_in, const int* in_sizes, int n_in,
                              void* d_out, int out_size, void* d_ws, size_t ws_size,
                              hipStream_t stream) {
    const float* X      = (const float*)d_in[0];   // (8192, 1024)
    const float* coeffs = (const float*)d_in[1];   // (1024, 5)
    const float* W      = (const float*)d_in[2];   // (1024, 2)
    const float* b      = (const float*)d_in[3];   // (1024,)
    float* Y            = (float*)d_out;           // (8192, 1024)

    kan_kernel<<<N_BLOCKS, 256, 0, stream>>>(X, coeffs, W, b, Y);
}